// Round 6
// baseline (314.930 us; speedup 1.0000x reference)
//
#include <hip/hip_runtime.h>
#include <hip/hip_bf16.h>

// WindowAttention3D: 3136 windows, N=64 tokens, C=128, H=4 heads, hd=32.
// One block per window, 4 waves, wave = head.
// v6 = v4 structure (136.5us best: full [64][40] staging, S=mfma(qf,kf),
// shuffle-free softmax w/ ones-MFMA row-sum, O in dead xs) + overlap attack:
//   - P double-buffer across attn bands (slots at buf+0 / buf+1280): band
//     mt+1's S/exp/stores overlap band mt's PV (v4 serialized on P reuse).
//   - proj weight software pipeline: proj_b + wproj tiles nt=0,1 prefetched
//     BEFORE barrier 3 (latency under barrier drain); tile nt+2 loaded under
//     tile nt's MFMAs. Removes the post-barrier L2-latency chain.
//   - TB bias (v5, verified): rpe_t [h][col][row] always; mask_t [w][col][row]
//     when ws permits; f32x4 loads, band-0 before barrier 2, band mt+1
//     prefetched under PV. Fallback !TB keeps v4 scalar mask loads.
//   - Q weights hoisted next to K weights before barrier 1.
// v5 lessons: occupancy is NOT LDS-capped (~39% at both 27.6/37.9KB) -> keep
// v4's 37888B LDS; halved/swapped staging added drains -> reverted.
//
// LDS map (bf16 elements):
//   [0, 8704)        xs  [64][136]  x staging -- later O staging [64][136]
//   [8704, 18944)    per-wave buf 2560 el: K [64][40] -> Q [64][40] ->
//                      V^T [32][72] -> P slots [16][72] at +0 and +1280

typedef __bf16 bf16x8 __attribute__((ext_vector_type(8)));
typedef __bf16 bf16x4 __attribute__((ext_vector_type(4)));
typedef float f32x4 __attribute__((ext_vector_type(4)));

#define NWMASK 392
#define SCALE 0.17677669529663687f  // 1/sqrt(32)

// ---------------- prep: weights->bf16, rpe_t gather, mask transpose ----------------
__global__ void prep(const float* __restrict__ qkv_w, const float* __restrict__ proj_w,
                     const float* __restrict__ tbl, const int* __restrict__ ridx,
                     __bf16* __restrict__ wqkv, __bf16* __restrict__ wproj,
                     float* __restrict__ rpe_t,
                     const float* __restrict__ mask, float* __restrict__ mask_t,
                     int do_mask) {
    __shared__ float t[64][65];
    if (blockIdx.x < 320) {
        int i = blockIdx.x * 256 + threadIdx.x;
        if (i < 49152) {
            wqkv[i] = (__bf16)qkv_w[i];                  // [384][128]
        } else if (i < 65536) {
            int j = i - 49152;  wproj[j] = (__bf16)proj_w[j];   // [128][128]
        } else {
            int j = i - 65536;                           // rpe_t [4][col 64][row 64]
            rpe_t[j] = tbl[ridx[(j & 63) * 64 + ((j >> 6) & 63)] * 4 + (j >> 12)];
        }
    } else {
        if (!do_mask) return;
        const int w = blockIdx.x - 320;                  // [392] windows
        const int c = threadIdx.x & 63, rb = threadIdx.x >> 6;
        const float* src = mask + (size_t)w * 4096;
        #pragma unroll
        for (int i = 0; i < 16; ++i) { int r = rb * 16 + i; t[r][c] = src[r * 64 + c]; }
        __syncthreads();
        float* dst = mask_t + (size_t)w * 4096;          // [w][col][row]
        #pragma unroll
        for (int i = 0; i < 16; ++i) { int r = rb * 16 + i; dst[r * 64 + c] = t[c][r]; }
    }
}

// ---------------- main fused kernel ----------------
// TB: mask_t transposed [w][col][row] available; else original [w][row][col].
template<bool TB>
__global__ __launch_bounds__(256, 4) void wattn_main(
    const float* __restrict__ x, const float* __restrict__ maskp,
    const float* __restrict__ qkv_b, const float* __restrict__ proj_b,
    const __bf16* __restrict__ wqkv, const __bf16* __restrict__ wproj,
    const float* __restrict__ rpe_t, float* __restrict__ out)
{
    __shared__ __align__(16) __bf16 smem[18944];   // 37888 B
    const int win  = blockIdx.x;
    const int tid  = threadIdx.x;
    const int h    = tid >> 6;        // wave id = head (and token band in proj)
    const int lane = tid & 63;
    const int quad = lane >> 4;
    const int l16  = lane & 15;

    __bf16* const xs  = smem;                     // [64][136]; O staging later
    __bf16* const buf = smem + 8704 + h * 2560;   // wave-private

    // ---- Phase 0: cooperative x staging, fp32 -> bf16, fully coalesced ----
    {
        const float* xb = x + (size_t)win * 8192;
        #pragma unroll
        for (int i = 0; i < 2; ++i) {
            const int row  = h * 16 + (lane >> 3) + i * 8;
            const int colg = (lane & 7) * 16;
            const float* xp = xb + row * 128 + colg;
            float4 a0 = *(const float4*)(xp);
            float4 a1 = *(const float4*)(xp + 4);
            float4 a2 = *(const float4*)(xp + 8);
            float4 a3 = *(const float4*)(xp + 12);
            bf16x8 t0, t1;
            t0[0]=(__bf16)a0.x; t0[1]=(__bf16)a0.y; t0[2]=(__bf16)a0.z; t0[3]=(__bf16)a0.w;
            t0[4]=(__bf16)a1.x; t0[5]=(__bf16)a1.y; t0[6]=(__bf16)a1.z; t0[7]=(__bf16)a1.w;
            t1[0]=(__bf16)a2.x; t1[1]=(__bf16)a2.y; t1[2]=(__bf16)a2.z; t1[3]=(__bf16)a2.w;
            t1[4]=(__bf16)a3.x; t1[5]=(__bf16)a3.y; t1[6]=(__bf16)a3.z; t1[7]=(__bf16)a3.w;
            *(bf16x8*)(xs + row * 136 + colg)     = t0;
            *(bf16x8*)(xs + row * 136 + colg + 8) = t1;
        }
    }

    // K and Q weights issued BEFORE barrier 1 (L2 latency under barrier wait).
    bf16x8 kwf[2][4]; float kbb[2];
    bf16x8 qwf[2][4]; float qbb[2];
    #pragma unroll
    for (int nt = 0; nt < 2; ++nt) {
        const int ngk = 128 + h * 32 + nt * 16 + l16;
        const int ngq = h * 32 + nt * 16 + l16;
        kbb[nt] = qkv_b[ngk];
        qbb[nt] = qkv_b[ngq];
        #pragma unroll
        for (int kt = 0; kt < 4; ++kt) {
            kwf[nt][kt] = *(const bf16x8*)(wqkv + ngk * 128 + kt * 32 + quad * 8);
            qwf[nt][kt] = *(const bf16x8*)(wqkv + ngq * 128 + kt * 32 + quad * 8);
        }
    }
    __syncthreads();   // barrier 1: xs ready

    bf16x8 kf[4], qf[4], vf[2][2];

    // ---- K phase: feats 128+h*32+[0,32) -> buf [64][40] -> kf (B-frags) ----
    {
        #pragma unroll
        for (int mt = 0; mt < 4; ++mt) {
            bf16x8 af[4];
            #pragma unroll
            for (int kt = 0; kt < 4; ++kt)
                af[kt] = *(const bf16x8*)(xs + (mt * 16 + l16) * 136 + kt * 32 + quad * 8);
            #pragma unroll
            for (int nt = 0; nt < 2; ++nt) {
                f32x4 acc = {0.f, 0.f, 0.f, 0.f};
                #pragma unroll
                for (int kt = 0; kt < 4; ++kt)
                    acc = __builtin_amdgcn_mfma_f32_16x16x32_bf16(af[kt], kwf[nt][kt], acc, 0, 0, 0);
                #pragma unroll
                for (int r = 0; r < 4; ++r)
                    buf[(mt * 16 + quad * 4 + r) * 40 + nt * 16 + l16] = (__bf16)(acc[r] + kbb[nt]);
            }
        }
        #pragma unroll
        for (int j = 0; j < 4; ++j)
            kf[j] = *(const bf16x8*)(buf + (j * 16 + l16) * 40 + quad * 8);
    }

    // ---- Q phase: feats h*32+[0,32), pre-scaled -> buf -> qf (A-frags) ----
    {
        #pragma unroll
        for (int mt = 0; mt < 4; ++mt) {
            bf16x8 af[4];
            #pragma unroll
            for (int kt = 0; kt < 4; ++kt)
                af[kt] = *(const bf16x8*)(xs + (mt * 16 + l16) * 136 + kt * 32 + quad * 8);
            #pragma unroll
            for (int nt = 0; nt < 2; ++nt) {
                f32x4 acc = {0.f, 0.f, 0.f, 0.f};
                #pragma unroll
                for (int kt = 0; kt < 4; ++kt)
                    acc = __builtin_amdgcn_mfma_f32_16x16x32_bf16(af[kt], qwf[nt][kt], acc, 0, 0, 0);
                #pragma unroll
                for (int r = 0; r < 4; ++r)
                    buf[(mt * 16 + quad * 4 + r) * 40 + nt * 16 + l16] = (__bf16)((acc[r] + qbb[nt]) * SCALE);
            }
        }
        #pragma unroll
        for (int mt = 0; mt < 4; ++mt)
            qf[mt] = *(const bf16x8*)(buf + (mt * 16 + l16) * 40 + quad * 8);
    }

    // ---- V phase: feats 256+h*32+[0,32) -> buf as V^T [32 feat][72 tok] -> vf ----
    {
        bf16x8 wf[2][4]; float bb[2];
        #pragma unroll
        for (int nt = 0; nt < 2; ++nt) {
            const int ng = 256 + h * 32 + nt * 16 + l16;
            bb[nt] = qkv_b[ng];
            #pragma unroll
            for (int kt = 0; kt < 4; ++kt)
                wf[nt][kt] = *(const bf16x8*)(wqkv + ng * 128 + kt * 32 + quad * 8);
        }
        #pragma unroll
        for (int mt = 0; mt < 4; ++mt) {
            bf16x8 af[4];
            #pragma unroll
            for (int kt = 0; kt < 4; ++kt)
                af[kt] = *(const bf16x8*)(xs + (mt * 16 + l16) * 136 + kt * 32 + quad * 8);
            #pragma unroll
            for (int nt = 0; nt < 2; ++nt) {
                f32x4 acc = {0.f, 0.f, 0.f, 0.f};
                #pragma unroll
                for (int kt = 0; kt < 4; ++kt)
                    acc = __builtin_amdgcn_mfma_f32_16x16x32_bf16(af[kt], wf[nt][kt], acc, 0, 0, 0);
                bf16x4 pk;
                #pragma unroll
                for (int r = 0; r < 4; ++r) pk[r] = (__bf16)(acc[r] + bb[nt]);
                *(bf16x4*)(buf + (nt * 16 + l16) * 72 + mt * 16 + quad * 4) = pk;
            }
        }
        #pragma unroll
        for (int kt = 0; kt < 2; ++kt)
            #pragma unroll
            for (int nf = 0; nf < 2; ++nf)
                vf[kt][nf] = *(const bf16x8*)(buf + (nf * 16 + l16) * 72 + kt * 32 + quad * 8);
    }

    // ---- bias band-0 prefetch: pure global loads, issue before barrier 2 ----
    const float* rt = rpe_t + h * 4096;                       // [col][row]
    const float* mw = maskp + (size_t)(win % NWMASK) * 4096;  // TB: [col][row]
    f32x4 rb4[4], mb4[4];
    #pragma unroll
    for (int nt = 0; nt < 4; ++nt) {
        rb4[nt] = *(const f32x4*)(rt + (nt * 16 + l16) * 64 + quad * 4);
        if constexpr (TB)
            mb4[nt] = *(const f32x4*)(mw + (nt * 16 + l16) * 64 + quad * 4);
    }
    __syncthreads();   // barrier 2: all xs reads done -> O staging overlay safe

    // ---- attention per 16-row band: S -> exp (no max-sub) -> P (double-
    //      buffered) -> PV + ones-MFMA row-sum -> O into xs ----
    bf16x8 onesf;
    #pragma unroll
    for (int j = 0; j < 8; ++j) onesf[j] = (__bf16)1.0f;

    #pragma unroll
    for (int mt = 0; mt < 4; ++mt) {
        __bf16* const pb = buf + (mt & 1) * 1280;   // P double-buffer slot
        f32x4 sc[4];
        #pragma unroll
        for (int nt = 0; nt < 4; ++nt) {
            f32x4 z = {0.f, 0.f, 0.f, 0.f};
            sc[nt] = __builtin_amdgcn_mfma_f32_16x16x32_bf16(qf[mt], kf[nt], z, 0, 0, 0);
        }
        float mbs[4][4];
        if constexpr (!TB) {   // fallback: v4-style coalesced scalar mask loads
            #pragma unroll
            for (int nt = 0; nt < 4; ++nt)
                #pragma unroll
                for (int r = 0; r < 4; ++r)
                    mbs[nt][r] = mw[(mt * 16 + quad * 4 + r) * 64 + nt * 16 + l16];
        }
        #pragma unroll
        for (int nt = 0; nt < 4; ++nt)
            #pragma unroll
            for (int r = 0; r < 4; ++r) {
                const float m = TB ? mb4[nt][r] : mbs[nt][r];
                pb[(quad * 4 + r) * 72 + nt * 16 + l16] =
                    (__bf16)__expf(sc[nt][r] + rb4[nt][r] + m);
            }
        // prefetch next band's biases (consumed above; PV below covers latency)
        if (mt < 3) {
            #pragma unroll
            for (int nt = 0; nt < 4; ++nt) {
                rb4[nt] = *(const f32x4*)(rt + (nt * 16 + l16) * 64 + (mt + 1) * 16 + quad * 4);
                if constexpr (TB)
                    mb4[nt] = *(const f32x4*)(mw + (nt * 16 + l16) * 64 + (mt + 1) * 16 + quad * 4);
            }
        }
        f32x4 oa[2] = {{0.f,0.f,0.f,0.f},{0.f,0.f,0.f,0.f}};
        f32x4 os = {0.f, 0.f, 0.f, 0.f};
        #pragma unroll
        for (int kt = 0; kt < 2; ++kt) {
            bf16x8 pf = *(const bf16x8*)(pb + l16 * 72 + kt * 32 + quad * 8);
            oa[0] = __builtin_amdgcn_mfma_f32_16x16x32_bf16(pf, vf[kt][0], oa[0], 0, 0, 0);
            oa[1] = __builtin_amdgcn_mfma_f32_16x16x32_bf16(pf, vf[kt][1], oa[1], 0, 0, 0);
            os    = __builtin_amdgcn_mfma_f32_16x16x32_bf16(pf, onesf,     os,    0, 0, 0);
        }
        #pragma unroll
        for (int r = 0; r < 4; ++r) {
            const float inv = 1.0f / os[r];
            const int orow = mt * 16 + quad * 4 + r;
            xs[orow * 136 + h * 32 + l16]      = (__bf16)(oa[0][r] * inv);
            xs[orow * 136 + h * 32 + 16 + l16] = (__bf16)(oa[1][r] * inv);
        }
    }

    // ---- proj prologue: bias + first two weight tiles BEFORE barrier 3 ----
    float pbv[8];
    #pragma unroll
    for (int nt = 0; nt < 8; ++nt) pbv[nt] = proj_b[nt * 16 + l16];
    bf16x8 wfp[2][4];
    #pragma unroll
    for (int t = 0; t < 2; ++t)
        #pragma unroll
        for (int kt = 0; kt < 4; ++kt)
            wfp[t][kt] = *(const bf16x8*)(wproj + (t * 16 + l16) * 128 + kt * 32 + quad * 8);
    __syncthreads();   // barrier 3: O staging (all heads) ready

    // ---- proj GEMM: wave h = token band, K=128; weights double-pipelined ----
    bf16x8 of[4];
    #pragma unroll
    for (int kt = 0; kt < 4; ++kt)
        of[kt] = *(const bf16x8*)(xs + (h * 16 + l16) * 136 + kt * 32 + quad * 8);
    #pragma unroll
    for (int nt = 0; nt < 8; ++nt) {
        f32x4 acc = {0.f, 0.f, 0.f, 0.f};
        #pragma unroll
        for (int kt = 0; kt < 4; ++kt)
            acc = __builtin_amdgcn_mfma_f32_16x16x32_bf16(of[kt], wfp[nt & 1][kt], acc, 0, 0, 0);
        if (nt < 6) {
            #pragma unroll
            for (int kt = 0; kt < 4; ++kt)
                wfp[nt & 1][kt] = *(const bf16x8*)(wproj + ((nt + 2) * 16 + l16) * 128 + kt * 32 + quad * 8);
        }
        float* dst = out + ((size_t)win * 64 + h * 16 + quad * 4) * 128 + nt * 16 + l16;
        #pragma unroll
        for (int r = 0; r < 4; ++r) dst[(size_t)r * 128] = acc[r] + pbv[nt];
    }
}

// ---------------- launch ----------------
extern "C" void kernel_launch(void* const* d_in, const int* in_sizes, int n_in,
                              void* d_out, int out_size, void* d_ws, size_t ws_size,
                              hipStream_t stream) {
    const float* x      = (const float*)d_in[0];
    const float* mask   = (const float*)d_in[1];
    const float* qkv_w  = (const float*)d_in[2];
    const float* qkv_b  = (const float*)d_in[3];
    const float* proj_w = (const float*)d_in[4];
    const float* proj_b = (const float*)d_in[5];
    const float* tbl    = (const float*)d_in[6];
    const int*   ridx   = (const int*)d_in[7];
    float* out = (float*)d_out;

    // ws: wqkv bf16 [384*128] | wproj bf16 [128*128] | rpe_t f32 [4][64][64]
    //     | mask_t f32 [392][64][64] (optional, 6.4MB)
    __bf16* wqkv  = (__bf16*)d_ws;
    __bf16* wproj = wqkv + 384 * 128;
    float*  rpe_t = (float*)((char*)d_ws + 131072);
    float*  mask_t = (float*)((char*)d_ws + 196608);
    const size_t need_tb = 196608 + (size_t)NWMASK * 4096 * 4;   // 6,619,136 B
    const bool tb = ws_size >= need_tb;

    prep<<<tb ? 712 : 320, 256, 0, stream>>>(qkv_w, proj_w, tbl, ridx,
                                             wqkv, wproj, rpe_t, mask, mask_t,
                                             tb ? 1 : 0);
    if (tb)
        wattn_main<true><<<3136, 256, 0, stream>>>(x, mask_t, qkv_b, proj_b,
                                                   wqkv, wproj, rpe_t, out);
    else
        wattn_main<false><<<3136, 256, 0, stream>>>(x, mask, qkv_b, proj_b,
                                                    wqkv, wproj, rpe_t, out);
}

// Round 7
// 309.679 us; speedup vs baseline: 1.0170x; 1.0170x over previous
//
#include <hip/hip_runtime.h>
#include <hip/hip_bf16.h>

// WindowAttention3D: 3136 windows, N=64 tokens, C=128, H=4 heads, hd=32.
// One block per window, 4 waves, wave = head.
// v7 = v4 (136.5us best) + ONLY register-neutral adds:
//   - P double-buffer across attn bands (LDS-only; slots buf+0 / buf+1280
//     overlay dead V^T staging): band mt+1 S/exp overlaps band mt PV.
//   - TB bias exactly as v5's spill-free attention loop: rpe_t [h][col][row]
//     always; mask_t [w][col][row] when ws permits; f32x4 loads, band-0
//     issued before barrier 2, band mt+1 prefetched under PV. !TB fallback
//     keeps v4 scalar mask loads.
// DROPPED from v6 (spill causes, +90MB scratch traffic): qwf hoist across
// K phase; proj weight pipeline across attn epilogue.
// Occupancy model (v5/v6 data): reg-capped at ~16 waves/CU (VGPR+AGPR~128),
// NOT LDS-capped -> keep v4's 37888B LDS; spill tripwire = WRITE_SIZE>100352KB.
//
// LDS map (bf16 elements):
//   [0, 8704)        xs  [64][136]  x staging -- later O staging [64][136]
//   [8704, 18944)    per-wave buf 2560 el: K [64][40] -> Q [64][40] ->
//                      V^T [32][72] -> P slots [16][72] at +0 and +1280

typedef __bf16 bf16x8 __attribute__((ext_vector_type(8)));
typedef __bf16 bf16x4 __attribute__((ext_vector_type(4)));
typedef float f32x4 __attribute__((ext_vector_type(4)));

#define NWMASK 392
#define SCALE 0.17677669529663687f  // 1/sqrt(32)

// ---------------- prep: weights->bf16, rpe_t gather, mask transpose ----------------
__global__ void prep(const float* __restrict__ qkv_w, const float* __restrict__ proj_w,
                     const float* __restrict__ tbl, const int* __restrict__ ridx,
                     __bf16* __restrict__ wqkv, __bf16* __restrict__ wproj,
                     float* __restrict__ rpe_t,
                     const float* __restrict__ mask, float* __restrict__ mask_t,
                     int do_mask) {
    __shared__ float t[64][65];
    if (blockIdx.x < 320) {
        int i = blockIdx.x * 256 + threadIdx.x;
        if (i < 49152) {
            wqkv[i] = (__bf16)qkv_w[i];                  // [384][128]
        } else if (i < 65536) {
            int j = i - 49152;  wproj[j] = (__bf16)proj_w[j];   // [128][128]
        } else {
            int j = i - 65536;                           // rpe_t [4][col 64][row 64]
            rpe_t[j] = tbl[ridx[(j & 63) * 64 + ((j >> 6) & 63)] * 4 + (j >> 12)];
        }
    } else {
        if (!do_mask) return;
        const int w = blockIdx.x - 320;                  // [392] windows
        const int c = threadIdx.x & 63, rb = threadIdx.x >> 6;
        const float* src = mask + (size_t)w * 4096;
        #pragma unroll
        for (int i = 0; i < 16; ++i) { int r = rb * 16 + i; t[r][c] = src[r * 64 + c]; }
        __syncthreads();
        float* dst = mask_t + (size_t)w * 4096;          // [w][col][row]
        #pragma unroll
        for (int i = 0; i < 16; ++i) { int r = rb * 16 + i; dst[r * 64 + c] = t[c][r]; }
    }
}

// ---------------- main fused kernel ----------------
// TB: mask_t transposed [w][col][row] available; else original [w][row][col].
template<bool TB>
__global__ __launch_bounds__(256, 4) void wattn_main(
    const float* __restrict__ x, const float* __restrict__ maskp,
    const float* __restrict__ qkv_b, const float* __restrict__ proj_b,
    const __bf16* __restrict__ wqkv, const __bf16* __restrict__ wproj,
    const float* __restrict__ rpe_t, float* __restrict__ out)
{
    __shared__ __align__(16) __bf16 smem[18944];   // 37888 B
    const int win  = blockIdx.x;
    const int tid  = threadIdx.x;
    const int h    = tid >> 6;        // wave id = head (and token band in proj)
    const int lane = tid & 63;
    const int quad = lane >> 4;
    const int l16  = lane & 15;

    __bf16* const xs  = smem;                     // [64][136]; O staging later
    __bf16* const buf = smem + 8704 + h * 2560;   // wave-private

    // ---- Phase 0: cooperative x staging, fp32 -> bf16, fully coalesced ----
    {
        const float* xb = x + (size_t)win * 8192;
        #pragma unroll
        for (int i = 0; i < 2; ++i) {
            const int row  = h * 16 + (lane >> 3) + i * 8;
            const int colg = (lane & 7) * 16;
            const float* xp = xb + row * 128 + colg;
            float4 a0 = *(const float4*)(xp);
            float4 a1 = *(const float4*)(xp + 4);
            float4 a2 = *(const float4*)(xp + 8);
            float4 a3 = *(const float4*)(xp + 12);
            bf16x8 t0, t1;
            t0[0]=(__bf16)a0.x; t0[1]=(__bf16)a0.y; t0[2]=(__bf16)a0.z; t0[3]=(__bf16)a0.w;
            t0[4]=(__bf16)a1.x; t0[5]=(__bf16)a1.y; t0[6]=(__bf16)a1.z; t0[7]=(__bf16)a1.w;
            t1[0]=(__bf16)a2.x; t1[1]=(__bf16)a2.y; t1[2]=(__bf16)a2.z; t1[3]=(__bf16)a2.w;
            t1[4]=(__bf16)a3.x; t1[5]=(__bf16)a3.y; t1[6]=(__bf16)a3.z; t1[7]=(__bf16)a3.w;
            *(bf16x8*)(xs + row * 136 + colg)     = t0;
            *(bf16x8*)(xs + row * 136 + colg + 8) = t1;
        }
    }

    // K-phase weights: issue global loads BEFORE the barrier so L2 latency
    // hides under the barrier wait + other waves' staging.
    bf16x8 kwf[2][4]; float kbb[2];
    #pragma unroll
    for (int nt = 0; nt < 2; ++nt) {
        const int ng = 128 + h * 32 + nt * 16 + l16;
        kbb[nt] = qkv_b[ng];
        #pragma unroll
        for (int kt = 0; kt < 4; ++kt)
            kwf[nt][kt] = *(const bf16x8*)(wqkv + ng * 128 + kt * 32 + quad * 8);
    }
    __syncthreads();   // barrier 1: xs ready

    bf16x8 kf[4], qf[4], vf[2][2];

    // ---- K phase: feats 128+h*32+[0,32) -> buf [64][40] -> kf (B-frags) ----
    {
        #pragma unroll
        for (int mt = 0; mt < 4; ++mt) {
            bf16x8 af[4];
            #pragma unroll
            for (int kt = 0; kt < 4; ++kt)
                af[kt] = *(const bf16x8*)(xs + (mt * 16 + l16) * 136 + kt * 32 + quad * 8);
            #pragma unroll
            for (int nt = 0; nt < 2; ++nt) {
                f32x4 acc = {0.f, 0.f, 0.f, 0.f};
                #pragma unroll
                for (int kt = 0; kt < 4; ++kt)
                    acc = __builtin_amdgcn_mfma_f32_16x16x32_bf16(af[kt], kwf[nt][kt], acc, 0, 0, 0);
                #pragma unroll
                for (int r = 0; r < 4; ++r)
                    buf[(mt * 16 + quad * 4 + r) * 40 + nt * 16 + l16] = (__bf16)(acc[r] + kbb[nt]);
            }
        }
        #pragma unroll
        for (int j = 0; j < 4; ++j)
            kf[j] = *(const bf16x8*)(buf + (j * 16 + l16) * 40 + quad * 8);
    }

    // ---- Q phase: feats h*32+[0,32), pre-scaled -> buf -> qf (A-frags) ----
    {
        bf16x8 wf[2][4]; float bb[2];
        #pragma unroll
        for (int nt = 0; nt < 2; ++nt) {
            const int ng = h * 32 + nt * 16 + l16;
            bb[nt] = qkv_b[ng];
            #pragma unroll
            for (int kt = 0; kt < 4; ++kt)
                wf[nt][kt] = *(const bf16x8*)(wqkv + ng * 128 + kt * 32 + quad * 8);
        }
        #pragma unroll
        for (int mt = 0; mt < 4; ++mt) {
            bf16x8 af[4];
            #pragma unroll
            for (int kt = 0; kt < 4; ++kt)
                af[kt] = *(const bf16x8*)(xs + (mt * 16 + l16) * 136 + kt * 32 + quad * 8);
            #pragma unroll
            for (int nt = 0; nt < 2; ++nt) {
                f32x4 acc = {0.f, 0.f, 0.f, 0.f};
                #pragma unroll
                for (int kt = 0; kt < 4; ++kt)
                    acc = __builtin_amdgcn_mfma_f32_16x16x32_bf16(af[kt], wf[nt][kt], acc, 0, 0, 0);
                #pragma unroll
                for (int r = 0; r < 4; ++r)
                    buf[(mt * 16 + quad * 4 + r) * 40 + nt * 16 + l16] = (__bf16)((acc[r] + bb[nt]) * SCALE);
            }
        }
        #pragma unroll
        for (int mt = 0; mt < 4; ++mt)
            qf[mt] = *(const bf16x8*)(buf + (mt * 16 + l16) * 40 + quad * 8);
    }

    // ---- V phase: feats 256+h*32+[0,32) -> buf as V^T [32 feat][72 tok] -> vf ----
    {
        bf16x8 wf[2][4]; float bb[2];
        #pragma unroll
        for (int nt = 0; nt < 2; ++nt) {
            const int ng = 256 + h * 32 + nt * 16 + l16;
            bb[nt] = qkv_b[ng];
            #pragma unroll
            for (int kt = 0; kt < 4; ++kt)
                wf[nt][kt] = *(const bf16x8*)(wqkv + ng * 128 + kt * 32 + quad * 8);
        }
        #pragma unroll
        for (int mt = 0; mt < 4; ++mt) {
            bf16x8 af[4];
            #pragma unroll
            for (int kt = 0; kt < 4; ++kt)
                af[kt] = *(const bf16x8*)(xs + (mt * 16 + l16) * 136 + kt * 32 + quad * 8);
            #pragma unroll
            for (int nt = 0; nt < 2; ++nt) {
                f32x4 acc = {0.f, 0.f, 0.f, 0.f};
                #pragma unroll
                for (int kt = 0; kt < 4; ++kt)
                    acc = __builtin_amdgcn_mfma_f32_16x16x32_bf16(af[kt], wf[nt][kt], acc, 0, 0, 0);
                bf16x4 pk;
                #pragma unroll
                for (int r = 0; r < 4; ++r) pk[r] = (__bf16)(acc[r] + bb[nt]);
                *(bf16x4*)(buf + (nt * 16 + l16) * 72 + mt * 16 + quad * 4) = pk;
            }
        }
        #pragma unroll
        for (int kt = 0; kt < 2; ++kt)
            #pragma unroll
            for (int nf = 0; nf < 2; ++nf)
                vf[kt][nf] = *(const bf16x8*)(buf + (nf * 16 + l16) * 72 + kt * 32 + quad * 8);
    }

    // ---- bias band-0 prefetch: pure global loads, issue before barrier 2 ----
    const float* rt = rpe_t + h * 4096;                       // [col][row]
    const float* mw = maskp + (size_t)(win % NWMASK) * 4096;  // TB: [col][row]
    f32x4 rb4[4], mb4[4];
    #pragma unroll
    for (int nt = 0; nt < 4; ++nt) {
        rb4[nt] = *(const f32x4*)(rt + (nt * 16 + l16) * 64 + quad * 4);
        if constexpr (TB)
            mb4[nt] = *(const f32x4*)(mw + (nt * 16 + l16) * 64 + quad * 4);
    }
    __syncthreads();   // barrier 2: all xs reads done -> O staging overlay safe

    // ---- attention per 16-row band: S -> exp (no max-sub) -> P (double-
    //      buffered) -> PV + ones-MFMA row-sum -> O into xs ----
    bf16x8 onesf;
    #pragma unroll
    for (int j = 0; j < 8; ++j) onesf[j] = (__bf16)1.0f;

    #pragma unroll
    for (int mt = 0; mt < 4; ++mt) {
        __bf16* const pb = buf + (mt & 1) * 1280;   // P double-buffer slot
        f32x4 sc[4];
        #pragma unroll
        for (int nt = 0; nt < 4; ++nt) {
            f32x4 z = {0.f, 0.f, 0.f, 0.f};
            sc[nt] = __builtin_amdgcn_mfma_f32_16x16x32_bf16(qf[mt], kf[nt], z, 0, 0, 0);
        }
        float mbs[4][4];
        if constexpr (!TB) {   // fallback: v4-style coalesced scalar mask loads
            #pragma unroll
            for (int nt = 0; nt < 4; ++nt)
                #pragma unroll
                for (int r = 0; r < 4; ++r)
                    mbs[nt][r] = mw[(mt * 16 + quad * 4 + r) * 64 + nt * 16 + l16];
        }
        #pragma unroll
        for (int nt = 0; nt < 4; ++nt)
            #pragma unroll
            for (int r = 0; r < 4; ++r) {
                const float m = TB ? mb4[nt][r] : mbs[nt][r];
                pb[(quad * 4 + r) * 72 + nt * 16 + l16] =
                    (__bf16)__expf(sc[nt][r] + rb4[nt][r] + m);
            }
        // prefetch next band's biases (consumed above; PV below covers latency)
        if (mt < 3) {
            #pragma unroll
            for (int nt = 0; nt < 4; ++nt) {
                rb4[nt] = *(const f32x4*)(rt + (nt * 16 + l16) * 64 + (mt + 1) * 16 + quad * 4);
                if constexpr (TB)
                    mb4[nt] = *(const f32x4*)(mw + (nt * 16 + l16) * 64 + (mt + 1) * 16 + quad * 4);
            }
        }
        f32x4 oa[2] = {{0.f,0.f,0.f,0.f},{0.f,0.f,0.f,0.f}};
        f32x4 os = {0.f, 0.f, 0.f, 0.f};
        #pragma unroll
        for (int kt = 0; kt < 2; ++kt) {
            bf16x8 pf = *(const bf16x8*)(pb + l16 * 72 + kt * 32 + quad * 8);
            oa[0] = __builtin_amdgcn_mfma_f32_16x16x32_bf16(pf, vf[kt][0], oa[0], 0, 0, 0);
            oa[1] = __builtin_amdgcn_mfma_f32_16x16x32_bf16(pf, vf[kt][1], oa[1], 0, 0, 0);
            os    = __builtin_amdgcn_mfma_f32_16x16x32_bf16(pf, onesf,     os,    0, 0, 0);
        }
        #pragma unroll
        for (int r = 0; r < 4; ++r) {
            const float inv = 1.0f / os[r];
            const int orow = mt * 16 + quad * 4 + r;
            xs[orow * 136 + h * 32 + l16]      = (__bf16)(oa[0][r] * inv);
            xs[orow * 136 + h * 32 + 16 + l16] = (__bf16)(oa[1][r] * inv);
        }
    }
    __syncthreads();   // barrier 3: O staging (all heads) ready

    // ---- proj GEMM: wave h = token band, K=128 over 4 heads' O ----
    bf16x8 of[4];
    #pragma unroll
    for (int kt = 0; kt < 4; ++kt)
        of[kt] = *(const bf16x8*)(xs + (h * 16 + l16) * 136 + kt * 32 + quad * 8);
    #pragma unroll
    for (int nt = 0; nt < 8; ++nt) {
        const int ng = nt * 16 + l16;
        const float b = proj_b[ng];
        bf16x8 wf[4];
        #pragma unroll
        for (int kt = 0; kt < 4; ++kt)
            wf[kt] = *(const bf16x8*)(wproj + ng * 128 + kt * 32 + quad * 8);
        f32x4 acc = {0.f, 0.f, 0.f, 0.f};
        #pragma unroll
        for (int kt = 0; kt < 4; ++kt)
            acc = __builtin_amdgcn_mfma_f32_16x16x32_bf16(of[kt], wf[kt], acc, 0, 0, 0);
        float* dst = out + ((size_t)win * 64 + h * 16 + quad * 4) * 128 + ng;
        #pragma unroll
        for (int r = 0; r < 4; ++r) dst[(size_t)r * 128] = acc[r] + b;
    }
}

// ---------------- launch ----------------
extern "C" void kernel_launch(void* const* d_in, const int* in_sizes, int n_in,
                              void* d_out, int out_size, void* d_ws, size_t ws_size,
                              hipStream_t stream) {
    const float* x      = (const float*)d_in[0];
    const float* mask   = (const float*)d_in[1];
    const float* qkv_w  = (const float*)d_in[2];
    const float* qkv_b  = (const float*)d_in[3];
    const float* proj_w = (const float*)d_in[4];
    const float* proj_b = (const float*)d_in[5];
    const float* tbl    = (const float*)d_in[6];
    const int*   ridx   = (const int*)d_in[7];
    float* out = (float*)d_out;

    // ws: wqkv bf16 [384*128] | wproj bf16 [128*128] | rpe_t f32 [4][64][64]
    //     | mask_t f32 [392][64][64] (optional, 6.4MB)
    __bf16* wqkv  = (__bf16*)d_ws;
    __bf16* wproj = wqkv + 384 * 128;
    float*  rpe_t = (float*)((char*)d_ws + 131072);
    float*  mask_t = (float*)((char*)d_ws + 196608);
    const size_t need_tb = 196608 + (size_t)NWMASK * 4096 * 4;   // 6,619,136 B
    const bool tb = ws_size >= need_tb;

    prep<<<tb ? 712 : 320, 256, 0, stream>>>(qkv_w, proj_w, tbl, ridx,
                                             wqkv, wproj, rpe_t, mask, mask_t,
                                             tb ? 1 : 0);
    if (tb)
        wattn_main<true><<<3136, 256, 0, stream>>>(x, mask_t, qkv_b, proj_b,
                                                   wqkv, wproj, rpe_t, out);
    else
        wattn_main<false><<<3136, 256, 0, stream>>>(x, mask, qkv_b, proj_b,
                                                    wqkv, wproj, rpe_t, out);
}

// Round 8
// 299.503 us; speedup vs baseline: 1.0515x; 1.0340x over previous
//
#include <hip/hip_runtime.h>
#include <hip/hip_bf16.h>

// WindowAttention3D: 3136 windows, N=64 tokens, C=128, H=4 heads, hd=32.
// One block per window, 4 waves, wave = head.
// v8 = v7 with __launch_bounds__(256,3).
// Register model (v6/v7 evidence): unified VGPR+AGPR ~128/wave == exactly the
// (256,4) budget (512-reg SIMD pool / 4 waves). Every addition spilled at
// constant reported VGPR=64. Measured occupancy ~12.5 waves/CU < 16-wave cap
// anyway -> (256,3) trades an unused cap (16->12) for budget 128->~170 so the
// TB-bias prefetch + P double-buffer can live in registers.
//   - P double-buffer across attn bands (slots buf+0 / buf+1280 overlay dead
//     V^T staging): band mt+1 S/exp overlaps band mt PV.
//   - TB bias: rpe_t [h][col][row]; mask_t [w][col][row] when ws permits;
//     f32x4 loads, band-0 before barrier 2, band mt+1 prefetched under PV.
//   - shuffle-free softmax (no max-sub, ones-MFMA row-sum), O in dead xs.
// Spill tripwire: WRITE_SIZE must be exactly 100352 KB.
//
// LDS map (bf16 elements):
//   [0, 8704)        xs  [64][136]  x staging -- later O staging [64][136]
//   [8704, 18944)    per-wave buf 2560 el: K [64][40] -> Q [64][40] ->
//                      V^T [32][72] -> P slots [16][72] at +0 and +1280

typedef __bf16 bf16x8 __attribute__((ext_vector_type(8)));
typedef __bf16 bf16x4 __attribute__((ext_vector_type(4)));
typedef float f32x4 __attribute__((ext_vector_type(4)));

#define NWMASK 392
#define SCALE 0.17677669529663687f  // 1/sqrt(32)

// ---------------- prep: weights->bf16, rpe_t gather, mask transpose ----------------
__global__ void prep(const float* __restrict__ qkv_w, const float* __restrict__ proj_w,
                     const float* __restrict__ tbl, const int* __restrict__ ridx,
                     __bf16* __restrict__ wqkv, __bf16* __restrict__ wproj,
                     float* __restrict__ rpe_t,
                     const float* __restrict__ mask, float* __restrict__ mask_t,
                     int do_mask) {
    __shared__ float t[64][65];
    if (blockIdx.x < 320) {
        int i = blockIdx.x * 256 + threadIdx.x;
        if (i < 49152) {
            wqkv[i] = (__bf16)qkv_w[i];                  // [384][128]
        } else if (i < 65536) {
            int j = i - 49152;  wproj[j] = (__bf16)proj_w[j];   // [128][128]
        } else {
            int j = i - 65536;                           // rpe_t [4][col 64][row 64]
            rpe_t[j] = tbl[ridx[(j & 63) * 64 + ((j >> 6) & 63)] * 4 + (j >> 12)];
        }
    } else {
        if (!do_mask) return;
        const int w = blockIdx.x - 320;                  // [392] windows
        const int c = threadIdx.x & 63, rb = threadIdx.x >> 6;
        const float* src = mask + (size_t)w * 4096;
        #pragma unroll
        for (int i = 0; i < 16; ++i) { int r = rb * 16 + i; t[r][c] = src[r * 64 + c]; }
        __syncthreads();
        float* dst = mask_t + (size_t)w * 4096;          // [w][col][row]
        #pragma unroll
        for (int i = 0; i < 16; ++i) { int r = rb * 16 + i; dst[r * 64 + c] = t[c][r]; }
    }
}

// ---------------- main fused kernel ----------------
// TB: mask_t transposed [w][col][row] available; else original [w][row][col].
template<bool TB>
__global__ __launch_bounds__(256, 3) void wattn_main(
    const float* __restrict__ x, const float* __restrict__ maskp,
    const float* __restrict__ qkv_b, const float* __restrict__ proj_b,
    const __bf16* __restrict__ wqkv, const __bf16* __restrict__ wproj,
    const float* __restrict__ rpe_t, float* __restrict__ out)
{
    __shared__ __align__(16) __bf16 smem[18944];   // 37888 B
    const int win  = blockIdx.x;
    const int tid  = threadIdx.x;
    const int h    = tid >> 6;        // wave id = head (and token band in proj)
    const int lane = tid & 63;
    const int quad = lane >> 4;
    const int l16  = lane & 15;

    __bf16* const xs  = smem;                     // [64][136]; O staging later
    __bf16* const buf = smem + 8704 + h * 2560;   // wave-private

    // ---- Phase 0: cooperative x staging, fp32 -> bf16, fully coalesced ----
    {
        const float* xb = x + (size_t)win * 8192;
        #pragma unroll
        for (int i = 0; i < 2; ++i) {
            const int row  = h * 16 + (lane >> 3) + i * 8;
            const int colg = (lane & 7) * 16;
            const float* xp = xb + row * 128 + colg;
            float4 a0 = *(const float4*)(xp);
            float4 a1 = *(const float4*)(xp + 4);
            float4 a2 = *(const float4*)(xp + 8);
            float4 a3 = *(const float4*)(xp + 12);
            bf16x8 t0, t1;
            t0[0]=(__bf16)a0.x; t0[1]=(__bf16)a0.y; t0[2]=(__bf16)a0.z; t0[3]=(__bf16)a0.w;
            t0[4]=(__bf16)a1.x; t0[5]=(__bf16)a1.y; t0[6]=(__bf16)a1.z; t0[7]=(__bf16)a1.w;
            t1[0]=(__bf16)a2.x; t1[1]=(__bf16)a2.y; t1[2]=(__bf16)a2.z; t1[3]=(__bf16)a2.w;
            t1[4]=(__bf16)a3.x; t1[5]=(__bf16)a3.y; t1[6]=(__bf16)a3.z; t1[7]=(__bf16)a3.w;
            *(bf16x8*)(xs + row * 136 + colg)     = t0;
            *(bf16x8*)(xs + row * 136 + colg + 8) = t1;
        }
    }

    // K-phase weights: issue global loads BEFORE the barrier so L2 latency
    // hides under the barrier wait + other waves' staging.
    bf16x8 kwf[2][4]; float kbb[2];
    #pragma unroll
    for (int nt = 0; nt < 2; ++nt) {
        const int ng = 128 + h * 32 + nt * 16 + l16;
        kbb[nt] = qkv_b[ng];
        #pragma unroll
        for (int kt = 0; kt < 4; ++kt)
            kwf[nt][kt] = *(const bf16x8*)(wqkv + ng * 128 + kt * 32 + quad * 8);
    }
    __syncthreads();   // barrier 1: xs ready

    bf16x8 kf[4], qf[4], vf[2][2];

    // ---- K phase: feats 128+h*32+[0,32) -> buf [64][40] -> kf (B-frags) ----
    {
        #pragma unroll
        for (int mt = 0; mt < 4; ++mt) {
            bf16x8 af[4];
            #pragma unroll
            for (int kt = 0; kt < 4; ++kt)
                af[kt] = *(const bf16x8*)(xs + (mt * 16 + l16) * 136 + kt * 32 + quad * 8);
            #pragma unroll
            for (int nt = 0; nt < 2; ++nt) {
                f32x4 acc = {0.f, 0.f, 0.f, 0.f};
                #pragma unroll
                for (int kt = 0; kt < 4; ++kt)
                    acc = __builtin_amdgcn_mfma_f32_16x16x32_bf16(af[kt], kwf[nt][kt], acc, 0, 0, 0);
                #pragma unroll
                for (int r = 0; r < 4; ++r)
                    buf[(mt * 16 + quad * 4 + r) * 40 + nt * 16 + l16] = (__bf16)(acc[r] + kbb[nt]);
            }
        }
        #pragma unroll
        for (int j = 0; j < 4; ++j)
            kf[j] = *(const bf16x8*)(buf + (j * 16 + l16) * 40 + quad * 8);
    }

    // ---- Q phase: feats h*32+[0,32), pre-scaled -> buf -> qf (A-frags) ----
    {
        bf16x8 wf[2][4]; float bb[2];
        #pragma unroll
        for (int nt = 0; nt < 2; ++nt) {
            const int ng = h * 32 + nt * 16 + l16;
            bb[nt] = qkv_b[ng];
            #pragma unroll
            for (int kt = 0; kt < 4; ++kt)
                wf[nt][kt] = *(const bf16x8*)(wqkv + ng * 128 + kt * 32 + quad * 8);
        }
        #pragma unroll
        for (int mt = 0; mt < 4; ++mt) {
            bf16x8 af[4];
            #pragma unroll
            for (int kt = 0; kt < 4; ++kt)
                af[kt] = *(const bf16x8*)(xs + (mt * 16 + l16) * 136 + kt * 32 + quad * 8);
            #pragma unroll
            for (int nt = 0; nt < 2; ++nt) {
                f32x4 acc = {0.f, 0.f, 0.f, 0.f};
                #pragma unroll
                for (int kt = 0; kt < 4; ++kt)
                    acc = __builtin_amdgcn_mfma_f32_16x16x32_bf16(af[kt], wf[nt][kt], acc, 0, 0, 0);
                #pragma unroll
                for (int r = 0; r < 4; ++r)
                    buf[(mt * 16 + quad * 4 + r) * 40 + nt * 16 + l16] = (__bf16)((acc[r] + bb[nt]) * SCALE);
            }
        }
        #pragma unroll
        for (int mt = 0; mt < 4; ++mt)
            qf[mt] = *(const bf16x8*)(buf + (mt * 16 + l16) * 40 + quad * 8);
    }

    // ---- V phase: feats 256+h*32+[0,32) -> buf as V^T [32 feat][72 tok] -> vf ----
    {
        bf16x8 wf[2][4]; float bb[2];
        #pragma unroll
        for (int nt = 0; nt < 2; ++nt) {
            const int ng = 256 + h * 32 + nt * 16 + l16;
            bb[nt] = qkv_b[ng];
            #pragma unroll
            for (int kt = 0; kt < 4; ++kt)
                wf[nt][kt] = *(const bf16x8*)(wqkv + ng * 128 + kt * 32 + quad * 8);
        }
        #pragma unroll
        for (int mt = 0; mt < 4; ++mt) {
            bf16x8 af[4];
            #pragma unroll
            for (int kt = 0; kt < 4; ++kt)
                af[kt] = *(const bf16x8*)(xs + (mt * 16 + l16) * 136 + kt * 32 + quad * 8);
            #pragma unroll
            for (int nt = 0; nt < 2; ++nt) {
                f32x4 acc = {0.f, 0.f, 0.f, 0.f};
                #pragma unroll
                for (int kt = 0; kt < 4; ++kt)
                    acc = __builtin_amdgcn_mfma_f32_16x16x32_bf16(af[kt], wf[nt][kt], acc, 0, 0, 0);
                bf16x4 pk;
                #pragma unroll
                for (int r = 0; r < 4; ++r) pk[r] = (__bf16)(acc[r] + bb[nt]);
                *(bf16x4*)(buf + (nt * 16 + l16) * 72 + mt * 16 + quad * 4) = pk;
            }
        }
        #pragma unroll
        for (int kt = 0; kt < 2; ++kt)
            #pragma unroll
            for (int nf = 0; nf < 2; ++nf)
                vf[kt][nf] = *(const bf16x8*)(buf + (nf * 16 + l16) * 72 + kt * 32 + quad * 8);
    }

    // ---- bias band-0 prefetch: pure global loads, issue before barrier 2 ----
    const float* rt = rpe_t + h * 4096;                       // [col][row]
    const float* mw = maskp + (size_t)(win % NWMASK) * 4096;  // TB: [col][row]
    f32x4 rb4[4], mb4[4];
    #pragma unroll
    for (int nt = 0; nt < 4; ++nt) {
        rb4[nt] = *(const f32x4*)(rt + (nt * 16 + l16) * 64 + quad * 4);
        if constexpr (TB)
            mb4[nt] = *(const f32x4*)(mw + (nt * 16 + l16) * 64 + quad * 4);
    }
    __syncthreads();   // barrier 2: all xs reads done -> O staging overlay safe

    // ---- attention per 16-row band: S -> exp (no max-sub) -> P (double-
    //      buffered) -> PV + ones-MFMA row-sum -> O into xs ----
    bf16x8 onesf;
    #pragma unroll
    for (int j = 0; j < 8; ++j) onesf[j] = (__bf16)1.0f;

    #pragma unroll
    for (int mt = 0; mt < 4; ++mt) {
        __bf16* const pb = buf + (mt & 1) * 1280;   // P double-buffer slot
        f32x4 sc[4];
        #pragma unroll
        for (int nt = 0; nt < 4; ++nt) {
            f32x4 z = {0.f, 0.f, 0.f, 0.f};
            sc[nt] = __builtin_amdgcn_mfma_f32_16x16x32_bf16(qf[mt], kf[nt], z, 0, 0, 0);
        }
        float mbs[4][4];
        if constexpr (!TB) {   // fallback: v4-style coalesced scalar mask loads
            #pragma unroll
            for (int nt = 0; nt < 4; ++nt)
                #pragma unroll
                for (int r = 0; r < 4; ++r)
                    mbs[nt][r] = mw[(mt * 16 + quad * 4 + r) * 64 + nt * 16 + l16];
        }
        #pragma unroll
        for (int nt = 0; nt < 4; ++nt)
            #pragma unroll
            for (int r = 0; r < 4; ++r) {
                const float m = TB ? mb4[nt][r] : mbs[nt][r];
                pb[(quad * 4 + r) * 72 + nt * 16 + l16] =
                    (__bf16)__expf(sc[nt][r] + rb4[nt][r] + m);
            }
        // prefetch next band's biases (consumed above; PV below covers latency)
        if (mt < 3) {
            #pragma unroll
            for (int nt = 0; nt < 4; ++nt) {
                rb4[nt] = *(const f32x4*)(rt + (nt * 16 + l16) * 64 + (mt + 1) * 16 + quad * 4);
                if constexpr (TB)
                    mb4[nt] = *(const f32x4*)(mw + (nt * 16 + l16) * 64 + (mt + 1) * 16 + quad * 4);
            }
        }
        f32x4 oa[2] = {{0.f,0.f,0.f,0.f},{0.f,0.f,0.f,0.f}};
        f32x4 os = {0.f, 0.f, 0.f, 0.f};
        #pragma unroll
        for (int kt = 0; kt < 2; ++kt) {
            bf16x8 pf = *(const bf16x8*)(pb + l16 * 72 + kt * 32 + quad * 8);
            oa[0] = __builtin_amdgcn_mfma_f32_16x16x32_bf16(pf, vf[kt][0], oa[0], 0, 0, 0);
            oa[1] = __builtin_amdgcn_mfma_f32_16x16x32_bf16(pf, vf[kt][1], oa[1], 0, 0, 0);
            os    = __builtin_amdgcn_mfma_f32_16x16x32_bf16(pf, onesf,     os,    0, 0, 0);
        }
        #pragma unroll
        for (int r = 0; r < 4; ++r) {
            const float inv = 1.0f / os[r];
            const int orow = mt * 16 + quad * 4 + r;
            xs[orow * 136 + h * 32 + l16]      = (__bf16)(oa[0][r] * inv);
            xs[orow * 136 + h * 32 + 16 + l16] = (__bf16)(oa[1][r] * inv);
        }
    }
    __syncthreads();   // barrier 3: O staging (all heads) ready

    // ---- proj GEMM: wave h = token band, K=128 over 4 heads' O ----
    bf16x8 of[4];
    #pragma unroll
    for (int kt = 0; kt < 4; ++kt)
        of[kt] = *(const bf16x8*)(xs + (h * 16 + l16) * 136 + kt * 32 + quad * 8);
    #pragma unroll
    for (int nt = 0; nt < 8; ++nt) {
        const int ng = nt * 16 + l16;
        const float b = proj_b[ng];
        bf16x8 wf[4];
        #pragma unroll
        for (int kt = 0; kt < 4; ++kt)
            wf[kt] = *(const bf16x8*)(wproj + ng * 128 + kt * 32 + quad * 8);
        f32x4 acc = {0.f, 0.f, 0.f, 0.f};
        #pragma unroll
        for (int kt = 0; kt < 4; ++kt)
            acc = __builtin_amdgcn_mfma_f32_16x16x32_bf16(of[kt], wf[kt], acc, 0, 0, 0);
        float* dst = out + ((size_t)win * 64 + h * 16 + quad * 4) * 128 + ng;
        #pragma unroll
        for (int r = 0; r < 4; ++r) dst[(size_t)r * 128] = acc[r] + b;
    }
}

// ---------------- launch ----------------
extern "C" void kernel_launch(void* const* d_in, const int* in_sizes, int n_in,
                              void* d_out, int out_size, void* d_ws, size_t ws_size,
                              hipStream_t stream) {
    const float* x      = (const float*)d_in[0];
    const float* mask   = (const float*)d_in[1];
    const float* qkv_w  = (const float*)d_in[2];
    const float* qkv_b  = (const float*)d_in[3];
    const float* proj_w = (const float*)d_in[4];
    const float* proj_b = (const float*)d_in[5];
    const float* tbl    = (const float*)d_in[6];
    const int*   ridx   = (const int*)d_in[7];
    float* out = (float*)d_out;

    // ws: wqkv bf16 [384*128] | wproj bf16 [128*128] | rpe_t f32 [4][64][64]
    //     | mask_t f32 [392][64][64] (optional, 6.4MB)
    __bf16* wqkv  = (__bf16*)d_ws;
    __bf16* wproj = wqkv + 384 * 128;
    float*  rpe_t = (float*)((char*)d_ws + 131072);
    float*  mask_t = (float*)((char*)d_ws + 196608);
    const size_t need_tb = 196608 + (size_t)NWMASK * 4096 * 4;   // 6,619,136 B
    const bool tb = ws_size >= need_tb;

    prep<<<tb ? 712 : 320, 256, 0, stream>>>(qkv_w, proj_w, tbl, ridx,
                                             wqkv, wproj, rpe_t, mask, mask_t,
                                             tb ? 1 : 0);
    if (tb)
        wattn_main<true><<<3136, 256, 0, stream>>>(x, mask_t, qkv_b, proj_b,
                                                   wqkv, wproj, rpe_t, out);
    else
        wattn_main<false><<<3136, 256, 0, stream>>>(x, mask, qkv_b, proj_b,
                                                    wqkv, wproj, rpe_t, out);
}

// Round 9
// 271.680 us; speedup vs baseline: 1.1592x; 1.1024x over previous
//
#include <hip/hip_runtime.h>
#include <hip/hip_bf16.h>

// WindowAttention3D: 3136 windows, N=64 tokens, C=128, H=4 heads, hd=32.
// One block per window, 4 waves, wave = head.
// v9 = v4 (136.5us best: (256,4), full-buffer staging, S=mfma(qf,kf),
// shuffle-free softmax w/ ones-MFMA row-sum, O in dead xs, single P buffer)
// + pre-summed bf16 bias table:
//   cb[h][w][row][col] = bf16(rpe[h][row][col] + mask[w][row][col])  (12.85MB)
//   Per attn band: 16 bf16 loads (v4-coalesced orientation) replace 32 f32
//   loads + 32 adds. Halves bias VMEM issue/bytes/VALU and 16 fewer transient
//   regs than v4 -> spill risk strictly lower. Fallback template = exact v4.
// Model (v4..v8 data): latency-bound, time ~ 1/resident-waves; reg wall 128
// at (256,4) -> only register-neutral chain-shorteners are admissible.
// Spill tripwire: WRITE_SIZE must be exactly 100352 KB.
//
// LDS map (bf16 elements):
//   [0, 8704)        xs  [64][136]  x staging -- later O staging [64][136]
//   [8704, 18944)    per-wave buf 2560 el: K [64][40] -> Q [64][40] ->
//                      V^T [32][72] -> P [16][72]

typedef __bf16 bf16x8 __attribute__((ext_vector_type(8)));
typedef __bf16 bf16x4 __attribute__((ext_vector_type(4)));
typedef float f32x4 __attribute__((ext_vector_type(4)));

#define NWMASK 392
#define SCALE 0.17677669529663687f  // 1/sqrt(32)

// ---------------- prep: weights->bf16, rpe gather, combined bias ----------------
// blocks 0..319: elementwise (wqkv, wproj, rpe f32 for fallback).
// blocks 320..1887: cb[h][w][4096] = bf16(tbl[ridx]*+mask), when do_comb.
__global__ void prep(const float* __restrict__ qkv_w, const float* __restrict__ proj_w,
                     const float* __restrict__ tbl, const int* __restrict__ ridx,
                     __bf16* __restrict__ wqkv, __bf16* __restrict__ wproj,
                     float* __restrict__ rpe,
                     const float* __restrict__ mask, __bf16* __restrict__ cb,
                     int do_comb) {
    if (blockIdx.x < 320) {
        int i = blockIdx.x * 256 + threadIdx.x;
        if (i < 49152) {
            wqkv[i] = (__bf16)qkv_w[i];                  // [384][128]
        } else if (i < 65536) {
            int j = i - 49152;  wproj[j] = (__bf16)proj_w[j];   // [128][128]
        } else {
            int j = i - 65536;                           // rpe [4][64][64] f32
            rpe[j] = tbl[ridx[j & 4095] * 4 + (j >> 12)];
        }
    } else {
        if (!do_comb) return;
        const int t = blockIdx.x - 320;                  // 0..1567 = h*392+w
        const int h = t / NWMASK;
        const int w = t - h * NWMASK;
        const float* mw = mask + (size_t)w * 4096;
        __bf16* dst = cb + ((size_t)t << 12);
        #pragma unroll
        for (int e = 0; e < 16; ++e) {
            const int idx = e * 256 + threadIdx.x;       // row*64+col
            dst[idx] = (__bf16)(tbl[ridx[idx] * 4 + h] + mw[idx]);
        }
    }
}

// ---------------- main fused kernel ----------------
// CB: combined bf16 bias table available; else v4 path (rpe f32 + mask f32).
template<bool CB>
__global__ __launch_bounds__(256, 4) void wattn_main(
    const float* __restrict__ x, const float* __restrict__ maskp,
    const float* __restrict__ qkv_b, const float* __restrict__ proj_b,
    const __bf16* __restrict__ wqkv, const __bf16* __restrict__ wproj,
    const float* __restrict__ rpe, const __bf16* __restrict__ cb,
    float* __restrict__ out)
{
    __shared__ __align__(16) __bf16 smem[18944];   // 37888 B
    const int win  = blockIdx.x;
    const int tid  = threadIdx.x;
    const int h    = tid >> 6;        // wave id = head (and token band in proj)
    const int lane = tid & 63;
    const int quad = lane >> 4;
    const int l16  = lane & 15;

    __bf16* const xs  = smem;                     // [64][136]; O staging later
    __bf16* const buf = smem + 8704 + h * 2560;   // wave-private

    // ---- Phase 0: cooperative x staging, fp32 -> bf16, fully coalesced ----
    {
        const float* xb = x + (size_t)win * 8192;
        #pragma unroll
        for (int i = 0; i < 2; ++i) {
            const int row  = h * 16 + (lane >> 3) + i * 8;
            const int colg = (lane & 7) * 16;
            const float* xp = xb + row * 128 + colg;
            float4 a0 = *(const float4*)(xp);
            float4 a1 = *(const float4*)(xp + 4);
            float4 a2 = *(const float4*)(xp + 8);
            float4 a3 = *(const float4*)(xp + 12);
            bf16x8 t0, t1;
            t0[0]=(__bf16)a0.x; t0[1]=(__bf16)a0.y; t0[2]=(__bf16)a0.z; t0[3]=(__bf16)a0.w;
            t0[4]=(__bf16)a1.x; t0[5]=(__bf16)a1.y; t0[6]=(__bf16)a1.z; t0[7]=(__bf16)a1.w;
            t1[0]=(__bf16)a2.x; t1[1]=(__bf16)a2.y; t1[2]=(__bf16)a2.z; t1[3]=(__bf16)a2.w;
            t1[4]=(__bf16)a3.x; t1[5]=(__bf16)a3.y; t1[6]=(__bf16)a3.z; t1[7]=(__bf16)a3.w;
            *(bf16x8*)(xs + row * 136 + colg)     = t0;
            *(bf16x8*)(xs + row * 136 + colg + 8) = t1;
        }
    }

    // K-phase weights: issue global loads BEFORE the barrier so L2 latency
    // hides under the barrier wait + other waves' staging.
    bf16x8 kwf[2][4]; float kbb[2];
    #pragma unroll
    for (int nt = 0; nt < 2; ++nt) {
        const int ng = 128 + h * 32 + nt * 16 + l16;
        kbb[nt] = qkv_b[ng];
        #pragma unroll
        for (int kt = 0; kt < 4; ++kt)
            kwf[nt][kt] = *(const bf16x8*)(wqkv + ng * 128 + kt * 32 + quad * 8);
    }
    __syncthreads();   // barrier 1: xs ready

    bf16x8 kf[4], qf[4], vf[2][2];

    // ---- K phase: feats 128+h*32+[0,32) -> buf [64][40] -> kf (B-frags) ----
    {
        #pragma unroll
        for (int mt = 0; mt < 4; ++mt) {
            bf16x8 af[4];
            #pragma unroll
            for (int kt = 0; kt < 4; ++kt)
                af[kt] = *(const bf16x8*)(xs + (mt * 16 + l16) * 136 + kt * 32 + quad * 8);
            #pragma unroll
            for (int nt = 0; nt < 2; ++nt) {
                f32x4 acc = {0.f, 0.f, 0.f, 0.f};
                #pragma unroll
                for (int kt = 0; kt < 4; ++kt)
                    acc = __builtin_amdgcn_mfma_f32_16x16x32_bf16(af[kt], kwf[nt][kt], acc, 0, 0, 0);
                #pragma unroll
                for (int r = 0; r < 4; ++r)
                    buf[(mt * 16 + quad * 4 + r) * 40 + nt * 16 + l16] = (__bf16)(acc[r] + kbb[nt]);
            }
        }
        #pragma unroll
        for (int j = 0; j < 4; ++j)
            kf[j] = *(const bf16x8*)(buf + (j * 16 + l16) * 40 + quad * 8);
    }

    // ---- Q phase: feats h*32+[0,32), pre-scaled -> buf -> qf (A-frags) ----
    {
        bf16x8 wf[2][4]; float bb[2];
        #pragma unroll
        for (int nt = 0; nt < 2; ++nt) {
            const int ng = h * 32 + nt * 16 + l16;
            bb[nt] = qkv_b[ng];
            #pragma unroll
            for (int kt = 0; kt < 4; ++kt)
                wf[nt][kt] = *(const bf16x8*)(wqkv + ng * 128 + kt * 32 + quad * 8);
        }
        #pragma unroll
        for (int mt = 0; mt < 4; ++mt) {
            bf16x8 af[4];
            #pragma unroll
            for (int kt = 0; kt < 4; ++kt)
                af[kt] = *(const bf16x8*)(xs + (mt * 16 + l16) * 136 + kt * 32 + quad * 8);
            #pragma unroll
            for (int nt = 0; nt < 2; ++nt) {
                f32x4 acc = {0.f, 0.f, 0.f, 0.f};
                #pragma unroll
                for (int kt = 0; kt < 4; ++kt)
                    acc = __builtin_amdgcn_mfma_f32_16x16x32_bf16(af[kt], wf[nt][kt], acc, 0, 0, 0);
                #pragma unroll
                for (int r = 0; r < 4; ++r)
                    buf[(mt * 16 + quad * 4 + r) * 40 + nt * 16 + l16] = (__bf16)((acc[r] + bb[nt]) * SCALE);
            }
        }
        #pragma unroll
        for (int mt = 0; mt < 4; ++mt)
            qf[mt] = *(const bf16x8*)(buf + (mt * 16 + l16) * 40 + quad * 8);
    }

    // ---- V phase: feats 256+h*32+[0,32) -> buf as V^T [32 feat][72 tok] -> vf ----
    {
        bf16x8 wf[2][4]; float bb[2];
        #pragma unroll
        for (int nt = 0; nt < 2; ++nt) {
            const int ng = 256 + h * 32 + nt * 16 + l16;
            bb[nt] = qkv_b[ng];
            #pragma unroll
            for (int kt = 0; kt < 4; ++kt)
                wf[nt][kt] = *(const bf16x8*)(wqkv + ng * 128 + kt * 32 + quad * 8);
        }
        #pragma unroll
        for (int mt = 0; mt < 4; ++mt) {
            bf16x8 af[4];
            #pragma unroll
            for (int kt = 0; kt < 4; ++kt)
                af[kt] = *(const bf16x8*)(xs + (mt * 16 + l16) * 136 + kt * 32 + quad * 8);
            #pragma unroll
            for (int nt = 0; nt < 2; ++nt) {
                f32x4 acc = {0.f, 0.f, 0.f, 0.f};
                #pragma unroll
                for (int kt = 0; kt < 4; ++kt)
                    acc = __builtin_amdgcn_mfma_f32_16x16x32_bf16(af[kt], wf[nt][kt], acc, 0, 0, 0);
                bf16x4 pk;
                #pragma unroll
                for (int r = 0; r < 4; ++r) pk[r] = (__bf16)(acc[r] + bb[nt]);
                *(bf16x4*)(buf + (nt * 16 + l16) * 72 + mt * 16 + quad * 4) = pk;
            }
        }
        #pragma unroll
        for (int kt = 0; kt < 2; ++kt)
            #pragma unroll
            for (int nf = 0; nf < 2; ++nf)
                vf[kt][nf] = *(const bf16x8*)(buf + (nf * 16 + l16) * 72 + kt * 32 + quad * 8);
    }
    __syncthreads();   // barrier 2: all xs reads done -> O staging overlay safe

    // ---- attention per 16-row band: S -> exp (no max-sub) -> P (buf) ->
    //      PV + ones-MFMA row-sum -> O into xs (stride 136, aligned) ----
    bf16x8 onesf;
    #pragma unroll
    for (int j = 0; j < 8; ++j) onesf[j] = (__bf16)1.0f;

    const __bf16* cbh  = CB ? cb + (((size_t)h * NWMASK + (win % NWMASK)) << 12) : nullptr;
    const float*  rpeh = rpe + h * 4096;
    const float*  mw   = maskp + (size_t)(win % NWMASK) * 4096;
    #pragma unroll
    for (int mt = 0; mt < 4; ++mt) {
        // hoisted bias loads, v4's coalesced pattern (consecutive l16 = cols)
        float bb[4][4];
        if constexpr (CB) {
            #pragma unroll
            for (int nt = 0; nt < 4; ++nt)
                #pragma unroll
                for (int r = 0; r < 4; ++r)
                    bb[nt][r] = (float)cbh[(mt * 16 + quad * 4 + r) * 64 + nt * 16 + l16];
        } else {
            #pragma unroll
            for (int nt = 0; nt < 4; ++nt)
                #pragma unroll
                for (int r = 0; r < 4; ++r) {
                    const int row = mt * 16 + quad * 4 + r;
                    bb[nt][r] = rpeh[row * 64 + nt * 16 + l16] + mw[row * 64 + nt * 16 + l16];
                }
        }
        f32x4 sc[4];
        #pragma unroll
        for (int nt = 0; nt < 4; ++nt) {
            f32x4 z = {0.f, 0.f, 0.f, 0.f};
            sc[nt] = __builtin_amdgcn_mfma_f32_16x16x32_bf16(qf[mt], kf[nt], z, 0, 0, 0);
        }
        // P band (16x64): exp without max-sub, C-layout -> wave-private buf
        #pragma unroll
        for (int nt = 0; nt < 4; ++nt)
            #pragma unroll
            for (int r = 0; r < 4; ++r)
                buf[(quad * 4 + r) * 72 + nt * 16 + l16] =
                    (__bf16)__expf(sc[nt][r] + bb[nt][r]);
        f32x4 oa[2] = {{0.f,0.f,0.f,0.f},{0.f,0.f,0.f,0.f}};
        f32x4 os = {0.f, 0.f, 0.f, 0.f};
        #pragma unroll
        for (int kt = 0; kt < 2; ++kt) {
            bf16x8 pf = *(const bf16x8*)(buf + l16 * 72 + kt * 32 + quad * 8);
            oa[0] = __builtin_amdgcn_mfma_f32_16x16x32_bf16(pf, vf[kt][0], oa[0], 0, 0, 0);
            oa[1] = __builtin_amdgcn_mfma_f32_16x16x32_bf16(pf, vf[kt][1], oa[1], 0, 0, 0);
            os    = __builtin_amdgcn_mfma_f32_16x16x32_bf16(pf, onesf,     os,    0, 0, 0);
        }
        #pragma unroll
        for (int r = 0; r < 4; ++r) {
            const float inv = 1.0f / os[r];
            const int orow = mt * 16 + quad * 4 + r;
            xs[orow * 136 + h * 32 + l16]      = (__bf16)(oa[0][r] * inv);
            xs[orow * 136 + h * 32 + 16 + l16] = (__bf16)(oa[1][r] * inv);
        }
    }
    __syncthreads();   // barrier 3: O staging (all heads) ready

    // ---- proj GEMM: wave h = token band, K=128 over 4 heads' O ----
    bf16x8 of[4];
    #pragma unroll
    for (int kt = 0; kt < 4; ++kt)
        of[kt] = *(const bf16x8*)(xs + (h * 16 + l16) * 136 + kt * 32 + quad * 8);
    #pragma unroll
    for (int nt = 0; nt < 8; ++nt) {
        const int ng = nt * 16 + l16;
        const float b = proj_b[ng];
        bf16x8 wf[4];
        #pragma unroll
        for (int kt = 0; kt < 4; ++kt)
            wf[kt] = *(const bf16x8*)(wproj + ng * 128 + kt * 32 + quad * 8);
        f32x4 acc = {0.f, 0.f, 0.f, 0.f};
        #pragma unroll
        for (int kt = 0; kt < 4; ++kt)
            acc = __builtin_amdgcn_mfma_f32_16x16x32_bf16(of[kt], wf[kt], acc, 0, 0, 0);
        float* dst = out + ((size_t)win * 64 + h * 16 + quad * 4) * 128 + ng;
        #pragma unroll
        for (int r = 0; r < 4; ++r) dst[(size_t)r * 128] = acc[r] + b;
    }
}

// ---------------- launch ----------------
extern "C" void kernel_launch(void* const* d_in, const int* in_sizes, int n_in,
                              void* d_out, int out_size, void* d_ws, size_t ws_size,
                              hipStream_t stream) {
    const float* x      = (const float*)d_in[0];
    const float* mask   = (const float*)d_in[1];
    const float* qkv_w  = (const float*)d_in[2];
    const float* qkv_b  = (const float*)d_in[3];
    const float* proj_w = (const float*)d_in[4];
    const float* proj_b = (const float*)d_in[5];
    const float* tbl    = (const float*)d_in[6];
    const int*   ridx   = (const int*)d_in[7];
    float* out = (float*)d_out;

    // ws: wqkv bf16 [384*128] | wproj bf16 [128*128] | rpe f32 [4][64][64]
    //     | cb bf16 [4][392][64][64] (optional, 12.85MB)
    __bf16* wqkv  = (__bf16*)d_ws;
    __bf16* wproj = wqkv + 384 * 128;
    float*  rpe   = (float*)((char*)d_ws + 131072);
    __bf16* cbp   = (__bf16*)((char*)d_ws + 196608);
    const size_t need_cb = 196608 + (size_t)4 * NWMASK * 4096 * 2;   // 13,041,664 B
    const bool comb = ws_size >= need_cb;

    prep<<<comb ? 1888 : 320, 256, 0, stream>>>(qkv_w, proj_w, tbl, ridx,
                                                wqkv, wproj, rpe, mask, cbp,
                                                comb ? 1 : 0);
    if (comb)
        wattn_main<true><<<3136, 256, 0, stream>>>(x, mask, qkv_b, proj_b,
                                                   wqkv, wproj, rpe, cbp, out);
    else
        wattn_main<false><<<3136, 256, 0, stream>>>(x, mask, qkv_b, proj_b,
                                                    wqkv, wproj, rpe, cbp, out);
}